// Round 1
// baseline (1283.341 us; speedup 1.0000x reference)
//
#include <hip/hip_runtime.h>
#include <math.h>

// PLDA pairwise scorer, eigendecomposition-free reformulation.
// out = 2 v_i^T B v_j - q_i - q_j - log_div,  B = (63/64) f(S_w^-1 S_b) S_w^-1,
// f(x) = (63/64) relu(x - 1/63) applied spectrally via Chebyshev poly (deg 28),
// S_w^-1 via Newton-Schulz. ||psi||^2 = tr(f(C)^2).

#define D 128
#define NCLS 256
#define NPC 64
#define MTEST 8192
#define COUNT (NCLS*NPC)
#define DEG 28

// ws layout (float offsets)
#define fMC    0          // 32768 class means [256][128]
#define fMEAN  32768      // 128
#define fSCAL  33000      // [0]=log_div [1]=inv_s [2]=c0 [3]=inv_h; coef at +8 (29); red at +48 (4)
#define fMAT   65536      // 10 matrices of 16384 floats
#define fBBF   262144     // B_bf16: 16384 ushorts
#define fPART  524288     // 64*16384 floats (K3 partials); later reused by U/V
#define fU     524288     // U_bf16: 8192*128 ushorts = 524288 float slots
#define fV     1048576    // V_bf16: same
#define fQ     1572864    // 8192 floats

using short8 = __attribute__((ext_vector_type(8))) short;
using f32x4  = __attribute__((ext_vector_type(4))) float;

__device__ inline unsigned short f2bf(float f) {
  unsigned u = __float_as_uint(f);
  unsigned r = u + 0x7FFFu + ((u >> 16) & 1u);
  return (unsigned short)(r >> 16);
}
__device__ inline float bf2f(unsigned short h) {
  return __uint_as_float(((unsigned)h) << 16);
}

__device__ inline float block_sum(float v, float* red, int tid) {
  #pragma unroll
  for (int off = 32; off > 0; off >>= 1) v += __shfl_down(v, off);
  __syncthreads();
  if ((tid & 63) == 0) red[tid >> 6] = v;
  __syncthreads();
  return red[0] + red[1] + red[2] + red[3];
}

// ---------------- K1: per-class means ----------------
__global__ void k_class_mean(const float* __restrict__ X, float* __restrict__ ws) {
  int k = blockIdx.x, d = threadIdx.x;
  const float* p = X + k * NPC * D + d;
  float s = 0.f;
  #pragma unroll
  for (int n = 0; n < NPC; n++) s += p[n * D];
  ws[fMC + k * D + d] = s * (1.0f / NPC);
}

// ---------------- K2: global mean ----------------
__global__ void k_global_mean(float* __restrict__ ws) {
  int d = threadIdx.x;
  float s = 0.f;
  for (int k = 0; k < NCLS; k++) s += ws[fMC + k * D + d];
  ws[fMEAN + d] = s * (1.0f / NCLS);
}

// ---------------- K3: Gt partials = X^T X over 256-row chunks (bf16 MFMA) ----------------
__global__ __launch_bounds__(256) void k_gt_partial(const float* __restrict__ X, float* __restrict__ ws) {
  __shared__ unsigned short xt[128 * 256]; // 64 KB, xt[d][s] transposed, swizzled
  int b = blockIdx.x, tid = threadIdx.x;
  const float* Xc = X + b * 256 * D;
  for (int idx = tid; idx < 256 * D; idx += 256) {
    int s = idx >> 7, d = idx & 127;
    unsigned byte = ((unsigned)(d * 512 + s * 2)) ^ (((unsigned)(d & 7)) << 4);
    *(unsigned short*)((char*)xt + byte) = f2bf(Xc[idx]);
  }
  __syncthreads();
  int w = tid >> 6, lane = tid & 63;
  int wr = (w >> 1) * 64, wc = (w & 1) * 64;
  f32x4 acc[4][4] = {};
  for (int ks = 0; ks < 8; ks++) {
    int kb = ks * 32 + (lane >> 4) * 8;
    short8 af[4];
    #pragma unroll
    for (int mt = 0; mt < 4; mt++) {
      int r = wr + mt * 16 + (lane & 15);
      unsigned byte = ((unsigned)(r * 512 + kb * 2)) ^ (((unsigned)(r & 7)) << 4);
      af[mt] = *(short8*)((char*)xt + byte);
    }
    #pragma unroll
    for (int nt = 0; nt < 4; nt++) {
      int c = wc + nt * 16 + (lane & 15);
      unsigned byte = ((unsigned)(c * 512 + kb * 2)) ^ (((unsigned)(c & 7)) << 4);
      short8 bfr = *(short8*)((char*)xt + byte);
      #pragma unroll
      for (int mt = 0; mt < 4; mt++)
        acc[mt][nt] = __builtin_amdgcn_mfma_f32_16x16x32_bf16(af[mt], bfr, acc[mt][nt], 0, 0, 0);
    }
  }
  float* outp = ws + fPART + b * 16384;
  #pragma unroll
  for (int mt = 0; mt < 4; mt++)
    #pragma unroll
    for (int nt = 0; nt < 4; nt++)
      #pragma unroll
      for (int r = 0; r < 4; r++) {
        int row = wr + mt * 16 + (lane >> 4) * 4 + r;
        int col = wc + nt * 16 + (lane & 15);
        outp[row * 128 + col] = acc[mt][nt][r];
      }
}

// ---------------- split-bf16 128x128x128 matmul: Cg = scale*(Ag·Bg) ----------------
// A read directly from global (rows), B staged transposed hi/lo in LDS.
// REQUIREMENT: Cg must not alias Ag or Bg.
__device__ void wg_mm(const float* Ag, const float* Bg, float* Cg, float scale,
                      unsigned short* Bhi, unsigned short* Blo, int tid) {
  __syncthreads();
  for (int idx = tid; idx < 16384; idx += 256) {
    int k = idx >> 7, c = idx & 127;
    float v = Bg[idx];
    unsigned short h = f2bf(v);
    unsigned short l = f2bf(v - bf2f(h));
    unsigned byte = ((unsigned)(c * 256 + k * 2)) ^ (((unsigned)(c & 7)) << 4);
    *(unsigned short*)((char*)Bhi + byte) = h;
    *(unsigned short*)((char*)Blo + byte) = l;
  }
  __syncthreads();
  int w = tid >> 6, lane = tid & 63;
  int wr = (w >> 1) * 64, wc = (w & 1) * 64;
  f32x4 acc[4][4] = {};
  for (int ks = 0; ks < 4; ks++) {
    int kb = ks * 32 + (lane >> 4) * 8;
    short8 ah[4], al[4];
    #pragma unroll
    for (int mt = 0; mt < 4; mt++) {
      int r = wr + mt * 16 + (lane & 15);
      const float* ap = Ag + r * 128 + kb;
      short8 hi, lo;
      #pragma unroll
      for (int i = 0; i < 8; i++) {
        float a = ap[i];
        unsigned short hb = f2bf(a);
        hi[i] = (short)hb;
        lo[i] = (short)f2bf(a - bf2f(hb));
      }
      ah[mt] = hi; al[mt] = lo;
    }
    #pragma unroll
    for (int nt = 0; nt < 4; nt++) {
      int c = wc + nt * 16 + (lane & 15);
      unsigned byte = ((unsigned)(c * 256 + kb * 2)) ^ (((unsigned)(c & 7)) << 4);
      short8 bh = *(short8*)((char*)Bhi + byte);
      short8 bl = *(short8*)((char*)Blo + byte);
      #pragma unroll
      for (int mt = 0; mt < 4; mt++) {
        f32x4 a0 = acc[mt][nt];
        a0 = __builtin_amdgcn_mfma_f32_16x16x32_bf16(ah[mt], bh, a0, 0, 0, 0);
        a0 = __builtin_amdgcn_mfma_f32_16x16x32_bf16(al[mt], bh, a0, 0, 0, 0);
        a0 = __builtin_amdgcn_mfma_f32_16x16x32_bf16(ah[mt], bl, a0, 0, 0, 0);
        acc[mt][nt] = a0;
      }
    }
  }
  #pragma unroll
  for (int mt = 0; mt < 4; mt++)
    #pragma unroll
    for (int nt = 0; nt < 4; nt++)
      #pragma unroll
      for (int r = 0; r < 4; r++) {
        int row = wr + mt * 16 + (lane >> 4) * 4 + r;
        int col = wc + nt * 16 + (lane & 15);
        Cg[row * 128 + col] = acc[mt][nt][r] * scale;
      }
  __syncthreads();
}

// ---------------- K4: the whole fit, single block ----------------
__global__ __launch_bounds__(256) void k_fit(float* __restrict__ ws) {
  __shared__ unsigned short sStage[32768]; // 64 KB
  int tid = threadIdx.x;
  float* SW = ws + fMAT;
  float* SB = SW + 16384;
  float* Zb = SB + 16384;
  float* Tb = Zb + 16384;
  float* Z2 = Tb + 16384;
  float* XH = Z2 + 16384;
  float* BA = XH + 16384;
  float* BB = BA + 16384;
  float* PP = BB + 16384;
  float* BM = PP + 16384;
  float* scal = ws + fSCAL;
  float* coef = ws + fSCAL + 8;
  float* red  = ws + fSCAL + 48;
  unsigned short* Bhi = sStage;
  unsigned short* Blo = sStage + 16384;

  // Phase 1: S_b = Mc^T Mc / 256 - m m^T (MFMA over K=256)
  {
    const float* Mc = ws + fMC;
    for (int idx = tid; idx < NCLS * D; idx += 256) {
      int kk = idx >> 7, dd = idx & 127;
      unsigned byte = ((unsigned)(dd * 512 + kk * 2)) ^ (((unsigned)(dd & 7)) << 4);
      *(unsigned short*)((char*)sStage + byte) = f2bf(Mc[idx]);
    }
    __syncthreads();
    int w = tid >> 6, lane = tid & 63;
    int wr = (w >> 1) * 64, wc = (w & 1) * 64;
    f32x4 acc[4][4] = {};
    for (int ks = 0; ks < 8; ks++) {
      int kb = ks * 32 + (lane >> 4) * 8;
      short8 af[4];
      #pragma unroll
      for (int mt = 0; mt < 4; mt++) {
        int r = wr + mt * 16 + (lane & 15);
        unsigned byte = ((unsigned)(r * 512 + kb * 2)) ^ (((unsigned)(r & 7)) << 4);
        af[mt] = *(short8*)((char*)sStage + byte);
      }
      #pragma unroll
      for (int nt = 0; nt < 4; nt++) {
        int c = wc + nt * 16 + (lane & 15);
        unsigned byte = ((unsigned)(c * 512 + kb * 2)) ^ (((unsigned)(c & 7)) << 4);
        short8 bfr = *(short8*)((char*)sStage + byte);
        #pragma unroll
        for (int mt = 0; mt < 4; mt++)
          acc[mt][nt] = __builtin_amdgcn_mfma_f32_16x16x32_bf16(af[mt], bfr, acc[mt][nt], 0, 0, 0);
      }
    }
    const float* mv = ws + fMEAN;
    #pragma unroll
    for (int mt = 0; mt < 4; mt++)
      #pragma unroll
      for (int nt = 0; nt < 4; nt++)
        #pragma unroll
        for (int r = 0; r < 4; r++) {
          int row = wr + mt * 16 + (lane >> 4) * 4 + r;
          int col = wc + nt * 16 + (lane & 15);
          SB[row * 128 + col] = acc[mt][nt][r] * (1.0f / 256.0f) - mv[row] * mv[col];
        }
    __syncthreads();
  }

  // Phase 2: reduce Gt partials -> S_w = Gt/count - SB - m m^T
  {
    const float* mv = ws + fMEAN;
    const float* part = ws + fPART;
    for (int idx = tid; idx < 16384; idx += 256) {
      float s = 0.f;
      for (int p = 0; p < 64; p++) s += part[p * 16384 + idx];
      int r = idx >> 7, c = idx & 127;
      SW[idx] = s * (1.0f / COUNT) - SB[idx] - mv[r] * mv[c];
    }
    __syncthreads();
  }

  // Phase 3: inv_s = 128/tr(S_w)
  {
    float v = 0.f;
    if (tid < 128) v = SW[tid * 129];
    float t = block_sum(v, red, tid);
    if (tid == 0) scal[1] = 128.0f / t;
    __syncthreads();
  }

  // Phase 4: Sn = S_w * inv_s (in place)
  {
    float is = scal[1];
    for (int idx = tid; idx < 16384; idx += 256) SW[idx] *= is;
    __syncthreads();
  }

  // Phase 5: Newton-Schulz: Z -> Sn^-1
  float* Zp = Zb; float* Zn = Z2;
  {
    for (int idx = tid; idx < 16384; idx += 256)
      Zp[idx] = ((idx >> 7) == (idx & 127)) ? 1.0f : 0.0f;
    for (int it = 0; it < 5; it++) {
      wg_mm(SW, Zp, Tb, 1.0f, Bhi, Blo, tid);
      for (int idx = tid; idx < 16384; idx += 256) {
        float dg = ((idx >> 7) == (idx & 127)) ? 2.0f : 0.0f;
        Tb[idx] = dg - Tb[idx];
      }
      wg_mm(Zp, Tb, Zn, 1.0f, Bhi, Blo, tid);
      float* tmp = Zp; Zp = Zn; Zn = tmp;
    }
  }

  // Phase 6: T = Z * S_b  (= s*C); tr(C^2); Chebyshev coefficients
  wg_mm(Zp, SB, Tb, 1.0f, Bhi, Blo, tid);
  {
    float local = 0.f;
    for (int idx = tid; idx < 16384; idx += 256) {
      int r = idx >> 7, c = idx & 127;
      local += Tb[idx] * Tb[c * 128 + r];
    }
    float t = block_sum(local, red, tid);
    if (tid == 0) {
      float is = scal[1];
      float trC2 = t * is * is;
      float Lam = 1.02f * sqrtf(fmaxf(trC2, 1e-30f));
      float lo = -0.02f * Lam, hi = Lam;
      float c0 = 0.5f * (hi + lo), hh = 0.5f * (hi - lo);
      float t0 = 1.0f / 63.0f;
      float x0 = (t0 - c0) / hh;
      x0 = fminf(fmaxf(x0, -1.0f), 1.0f);
      float th = acosf(x0);
      float SCc = 0.984375f * hh; // (63/64)*h
      const float PI = 3.14159265358979f;
      coef[0] = SCc * (2.0f / PI) * (sinf(th) - x0 * th);
      coef[1] = SCc * (2.0f / PI) * (0.5f * th + 0.25f * sinf(2.0f * th) - x0 * sinf(th));
      for (int j = 2; j <= DEG; j++) {
        float fj = (float)j;
        coef[j] = SCc * (2.0f / PI) *
          (0.5f * (sinf((fj + 1.0f) * th) / (fj + 1.0f) + sinf((fj - 1.0f) * th) / (fj - 1.0f))
           - x0 * sinf(fj * th) / fj);
      }
      scal[2] = c0; scal[3] = 1.0f / hh;
    }
    __syncthreads();
  }

  // Phase 7: XH = (T*inv_s - c0 I) * inv_h
  {
    float is = scal[1], c0 = scal[2], ih = scal[3];
    for (int idx = tid; idx < 16384; idx += 256) {
      float dg = ((idx >> 7) == (idx & 127)) ? c0 : 0.0f;
      XH[idx] = (Tb[idx] * is - dg) * ih;
    }
    __syncthreads();
  }

  // Phase 8: Clenshaw for F = f(C)
  float* pb1; float* pb2;
  {
    float aN = coef[DEG], aN1 = coef[DEG - 1];
    for (int idx = tid; idx < 16384; idx += 256) {
      float dg = ((idx >> 7) == (idx & 127)) ? 1.0f : 0.0f;
      BA[idx] = aN * dg;
      BB[idx] = aN1 * dg + 2.0f * aN * XH[idx];
    }
    pb1 = BB; pb2 = BA;
    for (int k = DEG - 2; k >= 1; k--) {
      wg_mm(XH, pb1, PP, 1.0f, Bhi, Blo, tid);
      float ak = coef[k];
      for (int idx = tid; idx < 16384; idx += 256) {
        float dg = ((idx >> 7) == (idx & 127)) ? 1.0f : 0.0f;
        pb2[idx] = ak * dg + 2.0f * PP[idx] - pb2[idx];
      }
      float* tmp = pb1; pb1 = pb2; pb2 = tmp;
    }
    wg_mm(XH, pb1, PP, 1.0f, Bhi, Blo, tid);
    float a0 = coef[0];
    for (int idx = tid; idx < 16384; idx += 256) {
      float dg = ((idx >> 7) == (idx & 127)) ? 1.0f : 0.0f;
      pb2[idx] = 0.5f * a0 * dg + PP[idx] - pb2[idx];
    }
    __syncthreads();
    // F = pb2
  }

  // Phase 9: ||psi||^2 = tr(F^2) -> log_div
  {
    float local = 0.f;
    for (int idx = tid; idx < 16384; idx += 256) {
      int r = idx >> 7, c = idx & 127;
      local += pb2[idx] * pb2[c * 128 + r];
    }
    float t = block_sum(local, red, tid);
    if (tid == 0) {
      float trF2 = fmaxf(t, 1e-30f);
      scal[0] = 0.5f * (128.0f * 1.8378770664093453f + 0.5f * logf(trF2));
    }
    __syncthreads();
  }

  // Phase 10: B = (63/64) * F * Z * inv_s
  wg_mm(pb2, Zp, BM, 0.984375f * scal[1], Bhi, Blo, tid);

  // Phase 11: symmetrize + bf16
  {
    unsigned short* Bbf = (unsigned short*)(ws + fBBF);
    for (int idx = tid; idx < 16384; idx += 256) {
      int r = idx >> 7, c = idx & 127;
      Bbf[idx] = f2bf(0.5f * (BM[idx] + BM[c * 128 + r]));
    }
  }
}

// ---------------- K5: V = test - mean (bf16); U = V*B (bf16) ----------------
__global__ __launch_bounds__(256) void k_latent(const float* __restrict__ test, float* __restrict__ ws) {
  __shared__ unsigned short vh[16384]; // 32 KB swizzled
  int blk = blockIdx.x, tid = threadIdx.x;
  const float* tb = test + blk * 128 * D;
  unsigned short* Vbf = (unsigned short*)(ws + fV);
  for (int idx = tid; idx < 16384; idx += 256) {
    int r = idx >> 7, c = idx & 127;
    float v = tb[idx] - ws[fMEAN + c];
    unsigned short h = f2bf(v);
    unsigned byte = ((unsigned)(r * 256 + c * 2)) ^ (((unsigned)(r & 7)) << 4);
    *(unsigned short*)((char*)vh + byte) = h;
    Vbf[blk * 16384 + idx] = h;
  }
  __syncthreads();
  int w = tid >> 6, lane = tid & 63;
  int wr = (w >> 1) * 64, wc = (w & 1) * 64;
  const unsigned short* Bbf = (const unsigned short*)(ws + fBBF);
  f32x4 acc[4][4] = {};
  for (int ks = 0; ks < 4; ks++) {
    int kb = ks * 32 + (lane >> 4) * 8;
    short8 af[4], bfv[4];
    #pragma unroll
    for (int mt = 0; mt < 4; mt++) {
      int r = wr + mt * 16 + (lane & 15);
      unsigned byte = ((unsigned)(r * 256 + kb * 2)) ^ (((unsigned)(r & 7)) << 4);
      af[mt] = *(short8*)((char*)vh + byte);
    }
    #pragma unroll
    for (int nt = 0; nt < 4; nt++) {
      int c = wc + nt * 16 + (lane & 15);
      bfv[nt] = *(const short8*)(Bbf + c * 128 + kb); // B symmetric: B[k][c]=B[c][k]
    }
    #pragma unroll
    for (int mt = 0; mt < 4; mt++)
      #pragma unroll
      for (int nt = 0; nt < 4; nt++)
        acc[mt][nt] = __builtin_amdgcn_mfma_f32_16x16x32_bf16(af[mt], bfv[nt], acc[mt][nt], 0, 0, 0);
  }
  unsigned short* Ubf = (unsigned short*)(ws + fU);
  #pragma unroll
  for (int mt = 0; mt < 4; mt++)
    #pragma unroll
    for (int nt = 0; nt < 4; nt++)
      #pragma unroll
      for (int r = 0; r < 4; r++) {
        int row = wr + mt * 16 + (lane >> 4) * 4 + r;
        int col = wc + nt * 16 + (lane & 15);
        Ubf[(blk * 128 + row) * 128 + col] = f2bf(acc[mt][nt][r]);
      }
}

// ---------------- K5b: q_i = U_i . V_i ----------------
__global__ void k_q(float* __restrict__ ws) {
  int i = blockIdx.x * 256 + threadIdx.x;
  const short8* U = (const short8*)((const unsigned short*)(ws + fU) + i * 128);
  const short8* V = (const short8*)((const unsigned short*)(ws + fV) + i * 128);
  float s = 0.f;
  for (int t = 0; t < 16; t++) {
    short8 u = U[t], v = V[t];
    #pragma unroll
    for (int j = 0; j < 8; j++)
      s += bf2f((unsigned short)u[j]) * bf2f((unsigned short)v[j]);
  }
  ws[fQ + i] = s;
}

// ---------------- K6: out = 2 U V^T - q_i - q_j - log_div ----------------
__global__ __launch_bounds__(256) void k_pair(const float* __restrict__ ws, float* __restrict__ out) {
  __shared__ float qi[128];
  __shared__ float qj[128];
  __shared__ float sld;
  int bi = blockIdx.x, bj = blockIdx.y, tid = threadIdx.x;
  if (tid < 128) qi[tid] = ws[fQ + bi * 128 + tid];
  else qj[tid - 128] = ws[fQ + bj * 128 + (tid - 128)];
  if (tid == 0) sld = ws[fSCAL + 0];
  __syncthreads();
  int w = tid >> 6, lane = tid & 63;
  int wr = (w >> 1) * 64, wc = (w & 1) * 64;
  const unsigned short* Ubf = (const unsigned short*)(ws + fU);
  const unsigned short* Vbf = (const unsigned short*)(ws + fV);
  f32x4 acc[4][4] = {};
  for (int ks = 0; ks < 4; ks++) {
    int kb = ks * 32 + (lane >> 4) * 8;
    short8 af[4], bfv[4];
    #pragma unroll
    for (int mt = 0; mt < 4; mt++) {
      int r = bi * 128 + wr + mt * 16 + (lane & 15);
      af[mt] = *(const short8*)(Ubf + r * 128 + kb);
    }
    #pragma unroll
    for (int nt = 0; nt < 4; nt++) {
      int c = bj * 128 + wc + nt * 16 + (lane & 15);
      bfv[nt] = *(const short8*)(Vbf + c * 128 + kb);
    }
    #pragma unroll
    for (int mt = 0; mt < 4; mt++)
      #pragma unroll
      for (int nt = 0; nt < 4; nt++)
        acc[mt][nt] = __builtin_amdgcn_mfma_f32_16x16x32_bf16(af[mt], bfv[nt], acc[mt][nt], 0, 0, 0);
  }
  float ld = sld;
  #pragma unroll
  for (int mt = 0; mt < 4; mt++)
    #pragma unroll
    for (int nt = 0; nt < 4; nt++)
      #pragma unroll
      for (int r = 0; r < 4; r++) {
        int row = wr + mt * 16 + (lane >> 4) * 4 + r;
        int col = wc + nt * 16 + (lane & 15);
        float g = acc[mt][nt][r];
        out[(size_t)(bi * 128 + row) * MTEST + (bj * 128 + col)] =
          2.0f * g - qi[row] - qj[col] - ld;
      }
}

extern "C" void kernel_launch(void* const* d_in, const int* in_sizes, int n_in,
                              void* d_out, int out_size, void* d_ws, size_t ws_size,
                              hipStream_t stream) {
  (void)in_sizes; (void)n_in; (void)out_size; (void)ws_size;
  const float* X = (const float*)d_in[0];    // src_seq [256,64,128]
  const float* test = (const float*)d_in[1]; // [8192,128]
  float* out = (float*)d_out;
  float* ws = (float*)d_ws;

  k_class_mean<<<NCLS, 128, 0, stream>>>(X, ws);
  k_global_mean<<<1, 128, 0, stream>>>(ws);
  k_gt_partial<<<64, 256, 0, stream>>>(X, ws);
  k_fit<<<1, 256, 0, stream>>>(ws);
  k_latent<<<64, 256, 0, stream>>>(test, ws);
  k_q<<<32, 256, 0, stream>>>(ws);
  k_pair<<<dim3(64, 64), 256, 0, stream>>>(ws, out);
}